// Round 14
// baseline (663.110 us; speedup 1.0000x reference)
//
#include <hip/hip_runtime.h>

#define NN 100000
#define NE 1600000
#define NBK 782    // ceil(NN/128) 128-node buckets
#define NCB 1024   // counting blocks in k_count
#define MAXB 2816  // slot stride per bucket; Poisson(2046)+17sigma, overflow ~1e-14

typedef __bf16 bf16x4 __attribute__((ext_vector_type(4)));
typedef __bf16 bf16x8 __attribute__((ext_vector_type(8)));
typedef float f32x2 __attribute__((ext_vector_type(2)));
typedef float f32x4 __attribute__((ext_vector_type(4)));

// dequant 8 fp8 (uint2), unconditional accumulate into acc[8] (zero-row padded gather)
#define ACC8_FP8(vv)                                                                  \
  {                                                                                   \
    f32x2 p;                                                                          \
    p = __builtin_amdgcn_cvt_pk_f32_fp8((vv).x, 0); acc[0] += p[0]; acc[1] += p[1];   \
    p = __builtin_amdgcn_cvt_pk_f32_fp8((vv).x, 1); acc[2] += p[0]; acc[3] += p[1];   \
    p = __builtin_amdgcn_cvt_pk_f32_fp8((vv).y, 0); acc[4] += p[0]; acc[5] += p[1];   \
    p = __builtin_amdgcn_cvt_pk_f32_fp8((vv).y, 1); acc[6] += p[0]; acc[7] += p[1];   \
  }

// ---------------- single-pass atomic bucket sort (replaces hist+scan+scatter) ----------------
// Within-bucket order was already nondeterministic (degfill cur[] atomics), so the
// stable 2-pass counting sort bought nothing. One edge pass: pos=atomicAdd(cnt[bk]),
// direct write into fixed-stride slots. 782 hot counters = cheap atomics (R13 lesson:
// it was the 100K-address random deg atomics that were expensive, not hot-set ones).
// W-prep fused as extra blocks.

__global__ __launch_bounds__(256) void k_count(const int* __restrict__ esrc, const int* __restrict__ edst,
                                               int* __restrict__ cnt, int* __restrict__ slot,
                                               const float* __restrict__ W0, const float* __restrict__ W1,
                                               const float* __restrict__ W2, __bf16* __restrict__ Wt) {
  int b = blockIdx.x;
  if (b >= NCB) {  // ---- W-prep range: 160 blocks, 40960 elems ----
    int i = (b - NCB) * 256 + threadIdx.x;
    if (i < 16384) {        // W0 128x128, i = k*128+n
      int k = i >> 7, n = i & 127;
      Wt[n * 128 + k] = (__bf16)W0[i];
    } else if (i < 32768) { // W1 128x128
      int j = i - 16384;
      int k = j >> 7, n = j & 127;
      Wt[16384 + n * 128 + k] = (__bf16)W1[j];
    } else if (i < 40960) { // W2 128x64, j = k*64+n
      int j = i - 32768;
      int k = j >> 6, n = j & 63;
      Wt[32768 + n * 128 + k] = (__bf16)W2[j];
    }
    return;
  }
  for (int e = b * 256 + threadIdx.x; e < NE; e += NCB * 256) {
    int d = edst[e];
    int bk = d >> 7;
    int pos = atomicAdd(&cnt[bk], 1);
    if (pos < MAXB) slot[(size_t)bk * MAXB + pos] = (esrc[e] << 7) | (d & 127);
  }
}

// 2-barrier wave-shfl scan over bucket counts (clamped to MAXB for consistency
// with any dropped-by-clamp edges)
__global__ __launch_bounds__(1024) void kB_bscan(const int* __restrict__ cnt, int* __restrict__ bptr) {
  __shared__ int ws[16];
  int tid = threadIdx.x, lane = tid & 63, w = tid >> 6;
  int v = (tid < NBK) ? min(cnt[tid], MAXB) : 0;
  int incl = v;
#pragma unroll
  for (int off = 1; off < 64; off <<= 1) {
    int t = __shfl_up(incl, off);
    if (lane >= off) incl += t;
  }
  if (lane == 63) ws[w] = incl;
  __syncthreads();
  if (tid < 16) {
    int s = ws[tid];
    int si = s;
#pragma unroll
    for (int off = 1; off < 16; off <<= 1) {
      int t = __shfl_up(si, off);
      if (lane >= off) si += t;
    }
    ws[tid] = si - s;  // exclusive prefix of wave sums
  }
  __syncthreads();
  if (tid < NBK) bptr[tid + 1] = incl + ws[w];
  if (tid == 0) bptr[0] = 0;
}

// per-bucket: node degrees + CSR compaction from strided slots
__global__ __launch_bounds__(256) void k_degfill(const int* __restrict__ slot, const int* __restrict__ cnt,
                                                 const int* __restrict__ bptr, int* __restrict__ row_ptr,
                                                 float* __restrict__ dis, int* __restrict__ csr_src) {
  __shared__ int deg[128];
  __shared__ int sc[128];
  __shared__ int cur[128];
  int b = blockIdx.x, tid = threadIdx.x;
  int nb0 = b << 7;
  int n = min(cnt[b], MAXB);
  const int* sl = slot + (size_t)b * MAXB;
  if (tid < 128) deg[tid] = 0;
  __syncthreads();
  for (int i = tid; i < n; i += 256) atomicAdd(&deg[sl[i] & 127], 1);
  __syncthreads();
  if (tid < 128) sc[tid] = deg[tid];
  __syncthreads();
  for (int off = 1; off < 128; off <<= 1) {
    int t = (tid >= off && tid < 128) ? sc[tid - off] : 0;
    __syncthreads();
    if (tid < 128) sc[tid] += t;
    __syncthreads();
  }
  int beg = bptr[b];
  if (tid < 128) {
    cur[tid] = beg + sc[tid] - deg[tid];
    if (nb0 + tid < NN) {
      row_ptr[nb0 + tid + 1] = beg + sc[tid];
      dis[nb0 + tid] = rsqrtf((float)(deg[tid] + 1));
      if (b == 0 && tid == 0) row_ptr[0] = 0;
    }
  }
  __syncthreads();
  for (int i = tid; i < n; i += 256) {
    int pk = sl[i];
    int pos = atomicAdd(&cur[pk & 127], 1);
    csr_src[pos] = pk >> 7;
  }
}

// ---------------- bf16 MFMA GEMM, 8-wave TLP variant (R9 exact — best measured) ----------------

template <int BN, int MODE, bool OUT8>
__global__ __launch_bounds__(512) void k_gemm(const void* __restrict__ Av, const __bf16* __restrict__ Wt,
                                              const float* __restrict__ bias, const float* __restrict__ dis,
                                              void* __restrict__ outv) {
  constexpr int LDK = 136;  // 128 + 8 pad: row stride 272 B -> 4-bank rotation
  constexpr int NT = BN / 32;
  constexpr int ROWB = BN * (OUT8 ? 1 : 2);  // bytes per output row
  __shared__ __bf16 lB[BN * LDK];

  const int tid = threadIdx.x;
  const int rowBase = blockIdx.x * 128;
  const int lane = tid & 63;
  const int wid = tid >> 6;              // 0..7
  const int wm = (wid & 3) * 32;         // 4 m-chunks of 32 rows
  const int wn = (wid >> 2) * (BN / 2);  // 2 n-chunks
  const int lm = lane & 15;
  const int kg = lane >> 4;

  if (blockIdx.x == 0 && tid < ROWB / 16) {  // zero pad row NN for agg gather
    ((uint4*)((char*)outv + (size_t)NN * ROWB))[tid] = make_uint4(0, 0, 0, 0);
  }

  for (int c = tid; c < 16 * BN; c += 512) {
    int n = c >> 4;
    int koff = (c & 15) * 8;
    *(bf16x8*)&lB[n * LDK + koff] = *(const bf16x8*)(Wt + n * 128 + koff);
  }
  __syncthreads();

  f32x4 acc[2][NT] = {};
  const bool full = (rowBase + 128 <= NN);

#pragma unroll 2
  for (int ks = 0; ks < 128; ks += 32) {
    int k0 = ks + kg * 8;
    bf16x8 af[2];
    if constexpr (MODE == 0) {
      const float* A = (const float*)Av;
#pragma unroll
      for (int tm = 0; tm < 2; ++tm) {
        int gr = rowBase + wm + tm * 16 + lm;
        f32x4 a0 = {}, a1 = {};
        if (full || gr < NN) {
          a0 = *(const f32x4*)(A + (size_t)gr * 128 + k0);
          a1 = *(const f32x4*)(A + (size_t)gr * 128 + k0 + 4);
        }
        af[tm] = bf16x8{(__bf16)a0[0], (__bf16)a0[1], (__bf16)a0[2], (__bf16)a0[3],
                        (__bf16)a1[0], (__bf16)a1[1], (__bf16)a1[2], (__bf16)a1[3]};
      }
    } else {
      const __bf16* A = (const __bf16*)Av;
      f32x4 b0 = *(const f32x4*)(bias + k0);
      f32x4 b1 = *(const f32x4*)(bias + k0 + 4);
#pragma unroll
      for (int tm = 0; tm < 2; ++tm) {
        int gr = rowBase + wm + tm * 16 + lm;
        bf16x8 v = {};
        if (full || gr < NN) v = *(const bf16x8*)(A + (size_t)gr * 128 + k0);
        af[tm] = bf16x8{(__bf16)fmaxf((float)v[0] + b0[0], 0.f), (__bf16)fmaxf((float)v[1] + b0[1], 0.f),
                        (__bf16)fmaxf((float)v[2] + b0[2], 0.f), (__bf16)fmaxf((float)v[3] + b0[3], 0.f),
                        (__bf16)fmaxf((float)v[4] + b1[0], 0.f), (__bf16)fmaxf((float)v[5] + b1[1], 0.f),
                        (__bf16)fmaxf((float)v[6] + b1[2], 0.f), (__bf16)fmaxf((float)v[7] + b1[3], 0.f)};
      }
    }
    bf16x8 bfr[NT];
#pragma unroll
    for (int tn = 0; tn < NT; ++tn)
      bfr[tn] = *(const bf16x8*)&lB[(wn + tn * 16 + lm) * LDK + k0];
#pragma unroll
    for (int tm = 0; tm < 2; ++tm)
#pragma unroll
      for (int tn = 0; tn < NT; ++tn)
        acc[tm][tn] = __builtin_amdgcn_mfma_f32_16x16x32_bf16(af[tm], bfr[tn], acc[tm][tn], 0, 0, 0);
  }

  // epilogue: C/D layout col=lane&15, row=(lane>>4)*4+reg; scale by dis[row]
#pragma unroll
  for (int tm = 0; tm < 2; ++tm) {
    int r0 = rowBase + wm + tm * 16 + kg * 4;
#pragma unroll
    for (int tn = 0; tn < NT; ++tn) {
      int c0 = wn + tn * 16 + lm;
#pragma unroll
      for (int r = 0; r < 4; ++r) {
        int gr = r0 + r;
        if (full || gr < NN) {
          float val = acc[tm][tn][r] * dis[gr];
          if constexpr (OUT8) {
            unsigned char* o8 = (unsigned char*)outv;
            unsigned pk = __builtin_amdgcn_cvt_pk_fp8_f32(val, val, 0, 0);
            o8[(size_t)gr * BN + c0] = (unsigned char)(pk & 0xffu);
          } else {
            __bf16* ob = (__bf16*)outv;
            ob[(size_t)gr * BN + c0] = (__bf16)val;
          }
        }
      }
    }
  }
}

// ---------------- node-quad pull aggregation (F=128, fp8 payload) ----------------
// 4 nodes/wave, one 16-lane group per node: one row_ptr/csr chain serves 4 nodes.

__global__ __launch_bounds__(256) void k_agg128(const unsigned char* __restrict__ tmp8, const int* __restrict__ row_ptr,
                                                const int* __restrict__ csr_src, const float* __restrict__ dis,
                                                __bf16* __restrict__ agg) {
  int qw = (blockIdx.x * 256 + threadIdx.x) >> 6;  // wave id; 4 nodes/wave, grid exact
  int lane = threadIdx.x & 63;
  int g = lane >> 4;        // group 0..3 -> node slot
  int fl = lane & 15;       // bytes [fl*8, fl*8+8)
  int node = qw * 4 + g;    // 25000 waves * 4 = 100000 = NN exactly

  int beg = row_ptr[node];
  int end = row_ptr[node + 1];

  // wave-uniform max degree over the 4 groups
  int mx = end - beg;
  mx = max(mx, __shfl_xor(mx, 16));
  mx = max(mx, __shfl_xor(mx, 32));

  float acc[8] = {};
  {
    uint2 sv = *(const uint2*)(tmp8 + (size_t)node * 128 + fl * 8);
    ACC8_FP8(sv);
  }

  for (int done = 0; done < mx; done += 16) {
    int ep = beg + done + fl;                       // this lane's edge slot (batch of 16/group)
    int sidx = (ep < end) ? csr_src[ep] : NN;       // coalesced per group; NN = zero row
    int rem = mx - done;                            // wave-uniform
    {
      uint2 v[8];
#pragma unroll
      for (int u = 0; u < 8; ++u) {
        int s = __shfl(sidx, g * 16 + u);
        v[u] = *(const uint2*)(tmp8 + (size_t)s * 128 + fl * 8);
      }
#pragma unroll
      for (int u = 0; u < 8; ++u) ACC8_FP8(v[u]);
    }
    if (rem > 8) {
      uint2 v[8];
#pragma unroll
      for (int u = 0; u < 8; ++u) {
        int s = __shfl(sidx, g * 16 + 8 + u);
        v[u] = *(const uint2*)(tmp8 + (size_t)s * 128 + fl * 8);
      }
#pragma unroll
      for (int u = 0; u < 8; ++u) ACC8_FP8(v[u]);
    }
  }

  // no cross-group reduce: group g's 16 lanes hold node's complete feature sums
  float d = dis[node];
  bf16x8 o;
#pragma unroll
  for (int t = 0; t < 8; ++t) o[t] = (__bf16)(acc[t] * d);
  *(bf16x8*)&agg[(size_t)node * 128 + fl * 8] = o;
}

// ---------------- node-quad F=64 aggregation + bias+relu+log_softmax ----------------

__global__ __launch_bounds__(256) void k_agg64_final(const __bf16* __restrict__ tmp, const int* __restrict__ row_ptr,
                                                     const int* __restrict__ csr_src, const float* __restrict__ dis,
                                                     const float* __restrict__ b2, float* __restrict__ out) {
  int qw = (blockIdx.x * 256 + threadIdx.x) >> 6;
  int lane = threadIdx.x & 63;
  int g = lane >> 4;        // group 0..3 -> node slot
  int fl = lane & 15;       // features [fl*4, fl*4+4)
  int node = qw * 4 + g;

  int beg = row_ptr[node];
  int end = row_ptr[node + 1];

  int mx = end - beg;
  mx = max(mx, __shfl_xor(mx, 16));
  mx = max(mx, __shfl_xor(mx, 32));

  float acc[4] = {};
  {
    bf16x4 sv = *(const bf16x4*)&tmp[(size_t)node * 64 + fl * 4];
#pragma unroll
    for (int t = 0; t < 4; ++t) acc[t] = (float)sv[t];
  }

  for (int done = 0; done < mx; done += 16) {
    int ep = beg + done + fl;
    int sidx = (ep < end) ? csr_src[ep] : NN;  // NN = zero row
    int rem = mx - done;
    {
      bf16x4 v[8];
#pragma unroll
      for (int u = 0; u < 8; ++u) {
        int s = __shfl(sidx, g * 16 + u);
        v[u] = *(const bf16x4*)&tmp[(size_t)s * 64 + fl * 4];
      }
#pragma unroll
      for (int u = 0; u < 8; ++u)
#pragma unroll
        for (int t = 0; t < 4; ++t) acc[t] += (float)v[u][t];
    }
    if (rem > 8) {
      bf16x4 v[8];
#pragma unroll
      for (int u = 0; u < 8; ++u) {
        int s = __shfl(sidx, g * 16 + 8 + u);
        v[u] = *(const bf16x4*)&tmp[(size_t)s * 64 + fl * 4];
      }
#pragma unroll
      for (int u = 0; u < 8; ++u)
#pragma unroll
        for (int t = 0; t < 4; ++t) acc[t] += (float)v[u][t];
    }
  }

  // bias + relu + log_softmax over 64 features (4/lane, reduce within 16-lane group)
  float d = dis[node];
  float v4[4], lm = -1e30f;
#pragma unroll
  for (int t = 0; t < 4; ++t) {
    v4[t] = fmaxf(acc[t] * d + b2[fl * 4 + t], 0.f);
    lm = fmaxf(lm, v4[t]);
  }
#pragma unroll
  for (int off = 8; off > 0; off >>= 1) lm = fmaxf(lm, __shfl_xor(lm, off));
  float le = 0.f;
#pragma unroll
  for (int t = 0; t < 4; ++t) le += __expf(v4[t] - lm);
#pragma unroll
  for (int off = 8; off > 0; off >>= 1) le += __shfl_xor(le, off);
  float ls = lm + __logf(le);
  f32x4 o = {v4[0] - ls, v4[1] - ls, v4[2] - ls, v4[3] - ls};
  *(f32x4*)&out[(size_t)node * 64 + fl * 4] = o;
}

// ---------------- launch ----------------

extern "C" void kernel_launch(void* const* d_in, const int* in_sizes, int n_in,
                              void* d_out, int out_size, void* d_ws, size_t ws_size,
                              hipStream_t stream) {
  const float* x  = (const float*)d_in[0];
  const int*   ei = (const int*)d_in[1];
  const float* W0 = (const float*)d_in[2];
  const float* b0 = (const float*)d_in[3];
  const float* W1 = (const float*)d_in[4];
  const float* b1 = (const float*)d_in[5];
  const float* W2 = (const float*)d_in[6];
  const float* b2 = (const float*)d_in[7];
  const int* esrc = ei;
  const int* edst = ei + NE;

  char* p = (char*)d_ws;
  auto alloc = [&](size_t bytes) {
    char* q = p;
    p += (bytes + 255) & ~(size_t)255;
    return q;
  };
  float*  dis     = (float*)alloc((size_t)NN * 4);
  int*    row_ptr = (int*)alloc((size_t)(NN + 1) * 4);
  int*    cnt     = (int*)alloc(NBK * 4);
  int*    bptr    = (int*)alloc((NBK + 1) * 4);
  __bf16* Wt      = (__bf16*)alloc(40960 * 2);                 // 80 KB: Wt0|Wt1|Wt2
  int*    csr_src = (int*)alloc((size_t)NE * 4);               // 6.4 MB
  char*   tmp     = (char*)alloc((size_t)(NN + 1) * 128 * 2);  // fp8/bf16 payload + zero row
  unsigned char* tmp8 = (unsigned char*)tmp;
  __bf16* tmp16   = (__bf16*)tmp;
  int*    slot    = (int*)tmp;                                 // 8.8 MB alias (consumed before GEMM0 writes tmp)

  hipMemsetAsync(cnt, 0, NBK * 4, stream);
  k_count<<<NCB + 160, 256, 0, stream>>>(esrc, edst, cnt, slot, W0, W1, W2, Wt);
  kB_bscan<<<1, 1024, 0, stream>>>(cnt, bptr);
  k_degfill<<<NBK, 256, 0, stream>>>(slot, cnt, bptr, row_ptr, dis, csr_src);

  int gblocks = (NN + 127) / 128;  // 782
  int ablocks = NN / 16;           // 6250: 4 waves/block x 4 nodes/wave

  k_gemm<128, 0, true><<<gblocks, 512, 0, stream>>>(x, Wt, nullptr, dis, tmp8);
  k_agg128<<<ablocks, 256, 0, stream>>>(tmp8, row_ptr, csr_src, dis, (__bf16*)d_out);

  k_gemm<128, 2, true><<<gblocks, 512, 0, stream>>>(d_out, Wt + 16384, b0, dis, tmp8);
  k_agg128<<<ablocks, 256, 0, stream>>>(tmp8, row_ptr, csr_src, dis, (__bf16*)d_out);

  k_gemm<64, 2, false><<<gblocks, 512, 0, stream>>>(d_out, Wt + 32768, b1, dis, tmp16);
  k_agg64_final<<<ablocks, 256, 0, stream>>>(tmp16, row_ptr, csr_src, dis, b2, (float*)d_out);
}

// Round 15
// 317.996 us; speedup vs baseline: 2.0853x; 2.0853x over previous
//
#include <hip/hip_runtime.h>

#define NN 100000
#define NE 1600000
#define NBK 782   // ceil(NN/128) 128-node buckets
#define NBLK 512  // sort blocks (R15: 256->512; tables still fit csr_src alias)
#define CHUNK ((NE + NBLK - 1) / NBLK)  // 3125

typedef __bf16 bf16x4 __attribute__((ext_vector_type(4)));
typedef __bf16 bf16x8 __attribute__((ext_vector_type(8)));
typedef float f32x2 __attribute__((ext_vector_type(2)));
typedef float f32x4 __attribute__((ext_vector_type(4)));

// dequant 8 fp8 (uint2), unconditional accumulate into acc[8] (zero-row padded gather)
#define ACC8_FP8(vv)                                                                  \
  {                                                                                   \
    f32x2 p;                                                                          \
    p = __builtin_amdgcn_cvt_pk_f32_fp8((vv).x, 0); acc[0] += p[0]; acc[1] += p[1];   \
    p = __builtin_amdgcn_cvt_pk_f32_fp8((vv).x, 1); acc[2] += p[0]; acc[3] += p[1];   \
    p = __builtin_amdgcn_cvt_pk_f32_fp8((vv).y, 0); acc[4] += p[0]; acc[5] += p[1];   \
    p = __builtin_amdgcn_cvt_pk_f32_fp8((vv).y, 1); acc[6] += p[0]; acc[7] += p[1];   \
  }

// ---------------- fused: privatized hist (blocks 0..NBLK-1) + W pre-transpose ----------------
// LDS-privatized atomics only (R13/R14 lessons: global atomics — random OR hot-set —
// are 10-100x more expensive than LDS ones).

__global__ __launch_bounds__(256) void k1_hist(const int* __restrict__ dst, int* __restrict__ bhist,
                                               const float* __restrict__ W0, const float* __restrict__ W1,
                                               const float* __restrict__ W2, __bf16* __restrict__ Wt) {
  int b = blockIdx.x;
  if (b >= NBLK) {  // ---- W-prep range: 160 blocks, 40960 elems ----
    int i = (b - NBLK) * 256 + threadIdx.x;
    if (i < 16384) {        // W0 128x128, i = k*128+n
      int k = i >> 7, n = i & 127;
      Wt[n * 128 + k] = (__bf16)W0[i];
    } else if (i < 32768) { // W1 128x128
      int j = i - 16384;
      int k = j >> 7, n = j & 127;
      Wt[16384 + n * 128 + k] = (__bf16)W1[j];
    } else if (i < 40960) { // W2 128x64, j = k*64+n
      int j = i - 32768;
      int k = j >> 6, n = j & 63;
      Wt[32768 + n * 128 + k] = (__bf16)W2[j];
    }
    return;
  }
  __shared__ int h[NBK];
  int tid = threadIdx.x;
  for (int i = tid; i < NBK; i += 256) h[i] = 0;
  __syncthreads();
  int base = b * CHUNK, end = min(base + CHUNK, NE);
  for (int e = base + tid; e < end; e += 256) atomicAdd(&h[dst[e] >> 7], 1);
  __syncthreads();
  for (int i = tid; i < NBK; i += 256) bhist[(size_t)i * NBLK + b] = h[i];
}

// per-bin total over NBLK=512 block-counts: 8 ints (2 x int4) per lane
__global__ __launch_bounds__(256) void kA2(const int* __restrict__ bhist, int* __restrict__ btot) {
  int w = threadIdx.x >> 6, lane = threadIdx.x & 63;
  int bin = blockIdx.x * 4 + w;
  if (bin >= NBK) return;
  const int* row = bhist + (size_t)bin * NBLK + lane * 8;
  int4 v0 = *(const int4*)(row);
  int4 v1 = *(const int4*)(row + 4);
  int s = v0.x + v0.y + v0.z + v0.w + v1.x + v1.y + v1.z + v1.w;
#pragma unroll
  for (int off = 32; off > 0; off >>= 1) s += __shfl_xor(s, off);
  if (lane == 0) btot[bin] = s;
}

// 2-barrier wave-shfl scan over NBK bucket totals
__global__ __launch_bounds__(1024) void kB_bscan(const int* __restrict__ btot, int* __restrict__ bptr) {
  __shared__ int ws[16];
  int tid = threadIdx.x, lane = tid & 63, w = tid >> 6;
  int v = (tid < NBK) ? btot[tid] : 0;
  int incl = v;
#pragma unroll
  for (int off = 1; off < 64; off <<= 1) {
    int t = __shfl_up(incl, off);
    if (lane >= off) incl += t;
  }
  if (lane == 63) ws[w] = incl;
  __syncthreads();
  if (tid < 16) {
    int s = ws[tid];
    int si = s;
#pragma unroll
    for (int off = 1; off < 16; off <<= 1) {
      int t = __shfl_up(si, off);
      if (lane >= off) si += t;
    }
    ws[tid] = si - s;  // exclusive prefix of wave sums
  }
  __syncthreads();
  if (tid < NBK) bptr[tid + 1] = incl + ws[w];
  if (tid == 0) bptr[0] = 0;
}

// per-bin exclusive prefix over NBLK=512 block-counts: lane owns 8 consecutive
__global__ __launch_bounds__(256) void kC2(const int* __restrict__ bhist, const int* __restrict__ bptr,
                                           int* __restrict__ blockbase) {
  int w = threadIdx.x >> 6, lane = threadIdx.x & 63;
  int bin = blockIdx.x * 4 + w;
  if (bin >= NBK) return;
  const int* row = bhist + (size_t)bin * NBLK + lane * 8;
  int4 q0 = *(const int4*)(row);
  int4 q1 = *(const int4*)(row + 4);
  int v[8] = {q0.x, q0.y, q0.z, q0.w, q1.x, q1.y, q1.z, q1.w};
  int s = 0;
#pragma unroll
  for (int i = 0; i < 8; ++i) s += v[i];
  int incl = s;
#pragma unroll
  for (int off = 1; off < 64; off <<= 1) {
    int t = __shfl_up(incl, off);
    if (lane >= off) incl += t;
  }
  int run = bptr[bin] + incl - s;
  int* out = blockbase + (size_t)bin * NBLK + lane * 8;
  int4 o0, o1;
  o0.x = run; run += v[0];
  o0.y = run; run += v[1];
  o0.z = run; run += v[2];
  o0.w = run; run += v[3];
  o1.x = run; run += v[4];
  o1.y = run; run += v[5];
  o1.z = run; run += v[6];
  o1.w = run; run += v[7];
  *(int4*)(out) = o0;
  *(int4*)(out + 4) = o1;
}

__global__ __launch_bounds__(256) void k3_scatter(const int* __restrict__ src, const int* __restrict__ dst,
                                                  const int* __restrict__ blockbase, int* __restrict__ bucketed) {
  __shared__ int cur[NBK];
  int tid = threadIdx.x, b = blockIdx.x;
  for (int i = tid; i < NBK; i += 256) cur[i] = blockbase[(size_t)i * NBLK + b];
  __syncthreads();
  int base = b * CHUNK, end = min(base + CHUNK, NE);
  for (int e = base + tid; e < end; e += 256) {
    int d = dst[e];
    int pos = atomicAdd(&cur[d >> 7], 1);
    bucketed[pos] = (src[e] << 7) | (d & 127);
  }
}

__global__ __launch_bounds__(256) void k_degfill(const int* __restrict__ bucketed, const int* __restrict__ bptr,
                                                 int* __restrict__ row_ptr, float* __restrict__ dis,
                                                 int* __restrict__ csr_src) {
  __shared__ int deg[128];
  __shared__ int sc[128];
  __shared__ int cur[128];
  int b = blockIdx.x, tid = threadIdx.x;
  int nb0 = b << 7;
  if (tid < 128) deg[tid] = 0;
  __syncthreads();
  int beg = bptr[b], end = bptr[b + 1];
  for (int e = beg + tid; e < end; e += 256) atomicAdd(&deg[bucketed[e] & 127], 1);
  __syncthreads();
  if (tid < 128) sc[tid] = deg[tid];
  __syncthreads();
  for (int off = 1; off < 128; off <<= 1) {
    int t = (tid >= off && tid < 128) ? sc[tid - off] : 0;
    __syncthreads();
    if (tid < 128) sc[tid] += t;
    __syncthreads();
  }
  if (tid < 128) {
    cur[tid] = beg + sc[tid] - deg[tid];
    if (nb0 + tid < NN) {
      row_ptr[nb0 + tid + 1] = beg + sc[tid];
      dis[nb0 + tid] = rsqrtf((float)(deg[tid] + 1));
      if (b == 0 && tid == 0) row_ptr[0] = 0;
    }
  }
  __syncthreads();
  for (int e = beg + tid; e < end; e += 256) {
    int pk = bucketed[e];
    int pos = atomicAdd(&cur[pk & 127], 1);
    csr_src[pos] = pk >> 7;
  }
}

// ---------------- bf16 MFMA GEMM, 8-wave TLP variant (R9 exact — best measured) ----------------

template <int BN, int MODE, bool OUT8>
__global__ __launch_bounds__(512) void k_gemm(const void* __restrict__ Av, const __bf16* __restrict__ Wt,
                                              const float* __restrict__ bias, const float* __restrict__ dis,
                                              void* __restrict__ outv) {
  constexpr int LDK = 136;  // 128 + 8 pad: row stride 272 B -> 4-bank rotation
  constexpr int NT = BN / 32;
  constexpr int ROWB = BN * (OUT8 ? 1 : 2);  // bytes per output row
  __shared__ __bf16 lB[BN * LDK];

  const int tid = threadIdx.x;
  const int rowBase = blockIdx.x * 128;
  const int lane = tid & 63;
  const int wid = tid >> 6;              // 0..7
  const int wm = (wid & 3) * 32;         // 4 m-chunks of 32 rows
  const int wn = (wid >> 2) * (BN / 2);  // 2 n-chunks
  const int lm = lane & 15;
  const int kg = lane >> 4;

  if (blockIdx.x == 0 && tid < ROWB / 16) {  // zero pad row NN for agg gather
    ((uint4*)((char*)outv + (size_t)NN * ROWB))[tid] = make_uint4(0, 0, 0, 0);
  }

  for (int c = tid; c < 16 * BN; c += 512) {
    int n = c >> 4;
    int koff = (c & 15) * 8;
    *(bf16x8*)&lB[n * LDK + koff] = *(const bf16x8*)(Wt + n * 128 + koff);
  }
  __syncthreads();

  f32x4 acc[2][NT] = {};
  const bool full = (rowBase + 128 <= NN);

#pragma unroll 2
  for (int ks = 0; ks < 128; ks += 32) {
    int k0 = ks + kg * 8;
    bf16x8 af[2];
    if constexpr (MODE == 0) {
      const float* A = (const float*)Av;
#pragma unroll
      for (int tm = 0; tm < 2; ++tm) {
        int gr = rowBase + wm + tm * 16 + lm;
        f32x4 a0 = {}, a1 = {};
        if (full || gr < NN) {
          a0 = *(const f32x4*)(A + (size_t)gr * 128 + k0);
          a1 = *(const f32x4*)(A + (size_t)gr * 128 + k0 + 4);
        }
        af[tm] = bf16x8{(__bf16)a0[0], (__bf16)a0[1], (__bf16)a0[2], (__bf16)a0[3],
                        (__bf16)a1[0], (__bf16)a1[1], (__bf16)a1[2], (__bf16)a1[3]};
      }
    } else {
      const __bf16* A = (const __bf16*)Av;
      f32x4 b0 = *(const f32x4*)(bias + k0);
      f32x4 b1 = *(const f32x4*)(bias + k0 + 4);
#pragma unroll
      for (int tm = 0; tm < 2; ++tm) {
        int gr = rowBase + wm + tm * 16 + lm;
        bf16x8 v = {};
        if (full || gr < NN) v = *(const bf16x8*)(A + (size_t)gr * 128 + k0);
        af[tm] = bf16x8{(__bf16)fmaxf((float)v[0] + b0[0], 0.f), (__bf16)fmaxf((float)v[1] + b0[1], 0.f),
                        (__bf16)fmaxf((float)v[2] + b0[2], 0.f), (__bf16)fmaxf((float)v[3] + b0[3], 0.f),
                        (__bf16)fmaxf((float)v[4] + b1[0], 0.f), (__bf16)fmaxf((float)v[5] + b1[1], 0.f),
                        (__bf16)fmaxf((float)v[6] + b1[2], 0.f), (__bf16)fmaxf((float)v[7] + b1[3], 0.f)};
      }
    }
    bf16x8 bfr[NT];
#pragma unroll
    for (int tn = 0; tn < NT; ++tn)
      bfr[tn] = *(const bf16x8*)&lB[(wn + tn * 16 + lm) * LDK + k0];
#pragma unroll
    for (int tm = 0; tm < 2; ++tm)
#pragma unroll
      for (int tn = 0; tn < NT; ++tn)
        acc[tm][tn] = __builtin_amdgcn_mfma_f32_16x16x32_bf16(af[tm], bfr[tn], acc[tm][tn], 0, 0, 0);
  }

  // epilogue: C/D layout col=lane&15, row=(lane>>4)*4+reg; scale by dis[row]
#pragma unroll
  for (int tm = 0; tm < 2; ++tm) {
    int r0 = rowBase + wm + tm * 16 + kg * 4;
#pragma unroll
    for (int tn = 0; tn < NT; ++tn) {
      int c0 = wn + tn * 16 + lm;
#pragma unroll
      for (int r = 0; r < 4; ++r) {
        int gr = r0 + r;
        if (full || gr < NN) {
          float val = acc[tm][tn][r] * dis[gr];
          if constexpr (OUT8) {
            unsigned char* o8 = (unsigned char*)outv;
            unsigned pk = __builtin_amdgcn_cvt_pk_fp8_f32(val, val, 0, 0);
            o8[(size_t)gr * BN + c0] = (unsigned char)(pk & 0xffu);
          } else {
            __bf16* ob = (__bf16*)outv;
            ob[(size_t)gr * BN + c0] = (__bf16)val;
          }
        }
      }
    }
  }
}

// ---------------- node-quad pull aggregation (F=128, fp8 payload) ----------------
// 4 nodes/wave, one 16-lane group per node: one row_ptr/csr chain serves 4 nodes.

__global__ __launch_bounds__(256) void k_agg128(const unsigned char* __restrict__ tmp8, const int* __restrict__ row_ptr,
                                                const int* __restrict__ csr_src, const float* __restrict__ dis,
                                                __bf16* __restrict__ agg) {
  int qw = (blockIdx.x * 256 + threadIdx.x) >> 6;  // wave id; 4 nodes/wave, grid exact
  int lane = threadIdx.x & 63;
  int g = lane >> 4;        // group 0..3 -> node slot
  int fl = lane & 15;       // bytes [fl*8, fl*8+8)
  int node = qw * 4 + g;    // 25000 waves * 4 = 100000 = NN exactly

  int beg = row_ptr[node];
  int end = row_ptr[node + 1];

  // wave-uniform max degree over the 4 groups
  int mx = end - beg;
  mx = max(mx, __shfl_xor(mx, 16));
  mx = max(mx, __shfl_xor(mx, 32));

  float acc[8] = {};
  {
    uint2 sv = *(const uint2*)(tmp8 + (size_t)node * 128 + fl * 8);
    ACC8_FP8(sv);
  }

  for (int done = 0; done < mx; done += 16) {
    int ep = beg + done + fl;                       // this lane's edge slot (batch of 16/group)
    int sidx = (ep < end) ? csr_src[ep] : NN;       // coalesced per group; NN = zero row
    int rem = mx - done;                            // wave-uniform
    {
      uint2 v[8];
#pragma unroll
      for (int u = 0; u < 8; ++u) {
        int s = __shfl(sidx, g * 16 + u);
        v[u] = *(const uint2*)(tmp8 + (size_t)s * 128 + fl * 8);
      }
#pragma unroll
      for (int u = 0; u < 8; ++u) ACC8_FP8(v[u]);
    }
    if (rem > 8) {
      uint2 v[8];
#pragma unroll
      for (int u = 0; u < 8; ++u) {
        int s = __shfl(sidx, g * 16 + 8 + u);
        v[u] = *(const uint2*)(tmp8 + (size_t)s * 128 + fl * 8);
      }
#pragma unroll
      for (int u = 0; u < 8; ++u) ACC8_FP8(v[u]);
    }
  }

  // no cross-group reduce: group g's 16 lanes hold node's complete feature sums
  float d = dis[node];
  bf16x8 o;
#pragma unroll
  for (int t = 0; t < 8; ++t) o[t] = (__bf16)(acc[t] * d);
  *(bf16x8*)&agg[(size_t)node * 128 + fl * 8] = o;
}

// ---------------- node-quad F=64 aggregation + bias+relu+log_softmax ----------------

__global__ __launch_bounds__(256) void k_agg64_final(const __bf16* __restrict__ tmp, const int* __restrict__ row_ptr,
                                                     const int* __restrict__ csr_src, const float* __restrict__ dis,
                                                     const float* __restrict__ b2, float* __restrict__ out) {
  int qw = (blockIdx.x * 256 + threadIdx.x) >> 6;
  int lane = threadIdx.x & 63;
  int g = lane >> 4;        // group 0..3 -> node slot
  int fl = lane & 15;       // features [fl*4, fl*4+4)
  int node = qw * 4 + g;

  int beg = row_ptr[node];
  int end = row_ptr[node + 1];

  int mx = end - beg;
  mx = max(mx, __shfl_xor(mx, 16));
  mx = max(mx, __shfl_xor(mx, 32));

  float acc[4] = {};
  {
    bf16x4 sv = *(const bf16x4*)&tmp[(size_t)node * 64 + fl * 4];
#pragma unroll
    for (int t = 0; t < 4; ++t) acc[t] = (float)sv[t];
  }

  for (int done = 0; done < mx; done += 16) {
    int ep = beg + done + fl;
    int sidx = (ep < end) ? csr_src[ep] : NN;  // NN = zero row
    int rem = mx - done;
    {
      bf16x4 v[8];
#pragma unroll
      for (int u = 0; u < 8; ++u) {
        int s = __shfl(sidx, g * 16 + u);
        v[u] = *(const bf16x4*)&tmp[(size_t)s * 64 + fl * 4];
      }
#pragma unroll
      for (int u = 0; u < 8; ++u)
#pragma unroll
        for (int t = 0; t < 4; ++t) acc[t] += (float)v[u][t];
    }
    if (rem > 8) {
      bf16x4 v[8];
#pragma unroll
      for (int u = 0; u < 8; ++u) {
        int s = __shfl(sidx, g * 16 + 8 + u);
        v[u] = *(const bf16x4*)&tmp[(size_t)s * 64 + fl * 4];
      }
#pragma unroll
      for (int u = 0; u < 8; ++u)
#pragma unroll
        for (int t = 0; t < 4; ++t) acc[t] += (float)v[u][t];
    }
  }

  // bias + relu + log_softmax over 64 features (4/lane, reduce within 16-lane group)
  float d = dis[node];
  float v4[4], lm = -1e30f;
#pragma unroll
  for (int t = 0; t < 4; ++t) {
    v4[t] = fmaxf(acc[t] * d + b2[fl * 4 + t], 0.f);
    lm = fmaxf(lm, v4[t]);
  }
#pragma unroll
  for (int off = 8; off > 0; off >>= 1) lm = fmaxf(lm, __shfl_xor(lm, off));
  float le = 0.f;
#pragma unroll
  for (int t = 0; t < 4; ++t) le += __expf(v4[t] - lm);
#pragma unroll
  for (int off = 8; off > 0; off >>= 1) le += __shfl_xor(le, off);
  float ls = lm + __logf(le);
  f32x4 o = {v4[0] - ls, v4[1] - ls, v4[2] - ls, v4[3] - ls};
  *(f32x4*)&out[(size_t)node * 64 + fl * 4] = o;
}

// ---------------- launch ----------------

extern "C" void kernel_launch(void* const* d_in, const int* in_sizes, int n_in,
                              void* d_out, int out_size, void* d_ws, size_t ws_size,
                              hipStream_t stream) {
  const float* x  = (const float*)d_in[0];
  const int*   ei = (const int*)d_in[1];
  const float* W0 = (const float*)d_in[2];
  const float* b0 = (const float*)d_in[3];
  const float* W1 = (const float*)d_in[4];
  const float* b1 = (const float*)d_in[5];
  const float* W2 = (const float*)d_in[6];
  const float* b2 = (const float*)d_in[7];
  const int* esrc = ei;
  const int* edst = ei + NE;

  char* p = (char*)d_ws;
  auto alloc = [&](size_t bytes) {
    char* q = p;
    p += (bytes + 255) & ~(size_t)255;
    return q;
  };
  float*  dis     = (float*)alloc((size_t)NN * 4);
  int*    row_ptr = (int*)alloc((size_t)(NN + 1) * 4);
  int*    btot    = (int*)alloc(NBK * 4);
  int*    bptr    = (int*)alloc((NBK + 1) * 4);
  __bf16* Wt      = (__bf16*)alloc(40960 * 2);                 // 80 KB: Wt0|Wt1|Wt2
  int*    csr_src = (int*)alloc((size_t)NE * 4);               // 6.4 MB
  char*   tmp     = (char*)alloc((size_t)(NN + 1) * 128 * 2);  // fp8/bf16 payload + zero row
  unsigned char* tmp8 = (unsigned char*)tmp;
  __bf16* tmp16   = (__bf16*)tmp;
  int*    bucketed  = (int*)tmp;                               // 6.4 MB alias (packed edges)
  int*    bhist     = csr_src;                                 // 1.6 MB alias [bin][block], 782*512 ints
  int*    blockbase = csr_src + NBK * NBLK;                    // 1.6 MB alias (fits: 800,768 < 1.6M ints)

  k1_hist<<<NBLK + 160, 256, 0, stream>>>(edst, bhist, W0, W1, W2, Wt);  // + fused W-prep
  kA2<<<(NBK + 3) / 4, 256, 0, stream>>>(bhist, btot);
  kB_bscan<<<1, 1024, 0, stream>>>(btot, bptr);
  kC2<<<(NBK + 3) / 4, 256, 0, stream>>>(bhist, bptr, blockbase);
  k3_scatter<<<NBLK, 256, 0, stream>>>(esrc, edst, blockbase, bucketed);
  k_degfill<<<NBK, 256, 0, stream>>>(bucketed, bptr, row_ptr, dis, csr_src);

  int gblocks = (NN + 127) / 128;  // 782
  int ablocks = NN / 16;           // 6250: 4 waves/block x 4 nodes/wave

  k_gemm<128, 0, true><<<gblocks, 512, 0, stream>>>(x, Wt, nullptr, dis, tmp8);
  k_agg128<<<ablocks, 256, 0, stream>>>(tmp8, row_ptr, csr_src, dis, (__bf16*)d_out);

  k_gemm<128, 2, true><<<gblocks, 512, 0, stream>>>(d_out, Wt + 16384, b0, dis, tmp8);
  k_agg128<<<ablocks, 256, 0, stream>>>(tmp8, row_ptr, csr_src, dis, (__bf16*)d_out);

  k_gemm<64, 2, false><<<gblocks, 512, 0, stream>>>(d_out, Wt + 32768, b1, dis, tmp16);
  k_agg64_final<<<ablocks, 256, 0, stream>>>(tmp16, row_ptr, csr_src, dis, b2, (float*)d_out);
}

// Round 16
// 311.092 us; speedup vs baseline: 2.1316x; 1.0222x over previous
//
#include <hip/hip_runtime.h>

#define NN 100000
#define NE 1600000
#define NBK 782   // ceil(NN/128) 128-node buckets
#define NBLK 512  // sort blocks (R15 best)
#define CHUNK ((NE + NBLK - 1) / NBLK)  // 3125

typedef __bf16 bf16x4 __attribute__((ext_vector_type(4)));
typedef __bf16 bf16x8 __attribute__((ext_vector_type(8)));
typedef float f32x2 __attribute__((ext_vector_type(2)));
typedef float f32x4 __attribute__((ext_vector_type(4)));

// dequant 8 fp8 (uint2), unconditional accumulate into acc[8] (zero-row padded gather)
#define ACC8_FP8(vv)                                                                  \
  {                                                                                   \
    f32x2 p;                                                                          \
    p = __builtin_amdgcn_cvt_pk_f32_fp8((vv).x, 0); acc[0] += p[0]; acc[1] += p[1];   \
    p = __builtin_amdgcn_cvt_pk_f32_fp8((vv).x, 1); acc[2] += p[0]; acc[3] += p[1];   \
    p = __builtin_amdgcn_cvt_pk_f32_fp8((vv).y, 0); acc[4] += p[0]; acc[5] += p[1];   \
    p = __builtin_amdgcn_cvt_pk_f32_fp8((vv).y, 1); acc[6] += p[0]; acc[7] += p[1];   \
  }

// ---------------- fused: privatized hist (blocks 0..NBLK-1) + W pre-transpose ----------------

__global__ __launch_bounds__(256) void k1_hist(const int* __restrict__ dst, int* __restrict__ bhist,
                                               const float* __restrict__ W0, const float* __restrict__ W1,
                                               const float* __restrict__ W2, __bf16* __restrict__ Wt) {
  int b = blockIdx.x;
  if (b >= NBLK) {  // ---- W-prep range: 160 blocks, 40960 elems ----
    int i = (b - NBLK) * 256 + threadIdx.x;
    if (i < 16384) {        // W0 128x128, i = k*128+n
      int k = i >> 7, n = i & 127;
      Wt[n * 128 + k] = (__bf16)W0[i];
    } else if (i < 32768) { // W1 128x128
      int j = i - 16384;
      int k = j >> 7, n = j & 127;
      Wt[16384 + n * 128 + k] = (__bf16)W1[j];
    } else if (i < 40960) { // W2 128x64, j = k*64+n
      int j = i - 32768;
      int k = j >> 6, n = j & 63;
      Wt[32768 + n * 128 + k] = (__bf16)W2[j];
    }
    return;
  }
  __shared__ int h[NBK];
  int tid = threadIdx.x;
  for (int i = tid; i < NBK; i += 256) h[i] = 0;
  __syncthreads();
  int base = b * CHUNK, end = min(base + CHUNK, NE);
  for (int e = base + tid; e < end; e += 256) atomicAdd(&h[dst[e] >> 7], 1);
  __syncthreads();
  for (int i = tid; i < NBK; i += 256) bhist[(size_t)i * NBLK + b] = h[i];
}

// per-bin total over NBLK=512 block-counts: 8 ints (2 x int4) per lane
__global__ __launch_bounds__(256) void kA2(const int* __restrict__ bhist, int* __restrict__ btot) {
  int w = threadIdx.x >> 6, lane = threadIdx.x & 63;
  int bin = blockIdx.x * 4 + w;
  if (bin >= NBK) return;
  const int* row = bhist + (size_t)bin * NBLK + lane * 8;
  int4 v0 = *(const int4*)(row);
  int4 v1 = *(const int4*)(row + 4);
  int s = v0.x + v0.y + v0.z + v0.w + v1.x + v1.y + v1.z + v1.w;
#pragma unroll
  for (int off = 32; off > 0; off >>= 1) s += __shfl_xor(s, off);
  if (lane == 0) btot[bin] = s;
}

// 2-barrier wave-shfl scan over NBK bucket totals
__global__ __launch_bounds__(1024) void kB_bscan(const int* __restrict__ btot, int* __restrict__ bptr) {
  __shared__ int ws[16];
  int tid = threadIdx.x, lane = tid & 63, w = tid >> 6;
  int v = (tid < NBK) ? btot[tid] : 0;
  int incl = v;
#pragma unroll
  for (int off = 1; off < 64; off <<= 1) {
    int t = __shfl_up(incl, off);
    if (lane >= off) incl += t;
  }
  if (lane == 63) ws[w] = incl;
  __syncthreads();
  if (tid < 16) {
    int s = ws[tid];
    int si = s;
#pragma unroll
    for (int off = 1; off < 16; off <<= 1) {
      int t = __shfl_up(si, off);
      if (lane >= off) si += t;
    }
    ws[tid] = si - s;  // exclusive prefix of wave sums
  }
  __syncthreads();
  if (tid < NBK) bptr[tid + 1] = incl + ws[w];
  if (tid == 0) bptr[0] = 0;
}

// per-bin exclusive prefix over NBLK=512 block-counts: lane owns 8 consecutive
__global__ __launch_bounds__(256) void kC2(const int* __restrict__ bhist, const int* __restrict__ bptr,
                                           int* __restrict__ blockbase) {
  int w = threadIdx.x >> 6, lane = threadIdx.x & 63;
  int bin = blockIdx.x * 4 + w;
  if (bin >= NBK) return;
  const int* row = bhist + (size_t)bin * NBLK + lane * 8;
  int4 q0 = *(const int4*)(row);
  int4 q1 = *(const int4*)(row + 4);
  int v[8] = {q0.x, q0.y, q0.z, q0.w, q1.x, q1.y, q1.z, q1.w};
  int s = 0;
#pragma unroll
  for (int i = 0; i < 8; ++i) s += v[i];
  int incl = s;
#pragma unroll
  for (int off = 1; off < 64; off <<= 1) {
    int t = __shfl_up(incl, off);
    if (lane >= off) incl += t;
  }
  int run = bptr[bin] + incl - s;
  int* out = blockbase + (size_t)bin * NBLK + lane * 8;
  int4 o0, o1;
  o0.x = run; run += v[0];
  o0.y = run; run += v[1];
  o0.z = run; run += v[2];
  o0.w = run; run += v[3];
  o1.x = run; run += v[4];
  o1.y = run; run += v[5];
  o1.z = run; run += v[6];
  o1.w = run; run += v[7];
  *(int4*)(out) = o0;
  *(int4*)(out + 4) = o1;
}

__global__ __launch_bounds__(256) void k3_scatter(const int* __restrict__ src, const int* __restrict__ dst,
                                                  const int* __restrict__ blockbase, int* __restrict__ bucketed) {
  __shared__ int cur[NBK];
  int tid = threadIdx.x, b = blockIdx.x;
  for (int i = tid; i < NBK; i += 256) cur[i] = blockbase[(size_t)i * NBLK + b];
  __syncthreads();
  int base = b * CHUNK, end = min(base + CHUNK, NE);
  for (int e = base + tid; e < end; e += 256) {
    int d = dst[e];
    int pos = atomicAdd(&cur[d >> 7], 1);
    bucketed[pos] = (src[e] << 7) | (d & 127);
  }
}

__global__ __launch_bounds__(256) void k_degfill(const int* __restrict__ bucketed, const int* __restrict__ bptr,
                                                 int* __restrict__ row_ptr, float* __restrict__ dis,
                                                 int* __restrict__ csr_src) {
  __shared__ int deg[128];
  __shared__ int sc[128];
  __shared__ int cur[128];
  int b = blockIdx.x, tid = threadIdx.x;
  int nb0 = b << 7;
  if (tid < 128) deg[tid] = 0;
  __syncthreads();
  int beg = bptr[b], end = bptr[b + 1];
  for (int e = beg + tid; e < end; e += 256) atomicAdd(&deg[bucketed[e] & 127], 1);
  __syncthreads();
  if (tid < 128) sc[tid] = deg[tid];
  __syncthreads();
  for (int off = 1; off < 128; off <<= 1) {
    int t = (tid >= off && tid < 128) ? sc[tid - off] : 0;
    __syncthreads();
    if (tid < 128) sc[tid] += t;
    __syncthreads();
  }
  if (tid < 128) {
    cur[tid] = beg + sc[tid] - deg[tid];
    if (nb0 + tid < NN) {
      row_ptr[nb0 + tid + 1] = beg + sc[tid];
      dis[nb0 + tid] = rsqrtf((float)(deg[tid] + 1));
      if (b == 0 && tid == 0) row_ptr[0] = 0;
    }
  }
  __syncthreads();
  for (int e = beg + tid; e < end; e += 256) {
    int pk = bucketed[e];
    int pos = atomicAdd(&cur[pk & 127], 1);
    csr_src[pos] = pk >> 7;
  }
}

// ---------------- bf16 MFMA GEMM (GEMM0 only: fp32 A from x) — R9 exact ----------------

template <int BN, int MODE, bool OUT8>
__global__ __launch_bounds__(512) void k_gemm(const void* __restrict__ Av, const __bf16* __restrict__ Wt,
                                              const float* __restrict__ bias, const float* __restrict__ dis,
                                              void* __restrict__ outv) {
  constexpr int LDK = 136;  // 128 + 8 pad
  constexpr int NT = BN / 32;
  constexpr int ROWB = BN * (OUT8 ? 1 : 2);
  __shared__ __bf16 lB[BN * LDK];

  const int tid = threadIdx.x;
  const int rowBase = blockIdx.x * 128;
  const int lane = tid & 63;
  const int wid = tid >> 6;
  const int wm = (wid & 3) * 32;
  const int wn = (wid >> 2) * (BN / 2);
  const int lm = lane & 15;
  const int kg = lane >> 4;

  if (blockIdx.x == 0 && tid < ROWB / 16) {  // zero pad row NN for agg gather
    ((uint4*)((char*)outv + (size_t)NN * ROWB))[tid] = make_uint4(0, 0, 0, 0);
  }

  for (int c = tid; c < 16 * BN; c += 512) {
    int n = c >> 4;
    int koff = (c & 15) * 8;
    *(bf16x8*)&lB[n * LDK + koff] = *(const bf16x8*)(Wt + n * 128 + koff);
  }
  __syncthreads();

  f32x4 acc[2][NT] = {};
  const bool full = (rowBase + 128 <= NN);

#pragma unroll 2
  for (int ks = 0; ks < 128; ks += 32) {
    int k0 = ks + kg * 8;
    bf16x8 af[2];
    const float* A = (const float*)Av;
#pragma unroll
    for (int tm = 0; tm < 2; ++tm) {
      int gr = rowBase + wm + tm * 16 + lm;
      f32x4 a0 = {}, a1 = {};
      if (full || gr < NN) {
        a0 = *(const f32x4*)(A + (size_t)gr * 128 + k0);
        a1 = *(const f32x4*)(A + (size_t)gr * 128 + k0 + 4);
      }
      af[tm] = bf16x8{(__bf16)a0[0], (__bf16)a0[1], (__bf16)a0[2], (__bf16)a0[3],
                      (__bf16)a1[0], (__bf16)a1[1], (__bf16)a1[2], (__bf16)a1[3]};
    }
    bf16x8 bfr[NT];
#pragma unroll
    for (int tn = 0; tn < NT; ++tn)
      bfr[tn] = *(const bf16x8*)&lB[(wn + tn * 16 + lm) * LDK + k0];
#pragma unroll
    for (int tm = 0; tm < 2; ++tm)
#pragma unroll
      for (int tn = 0; tn < NT; ++tn)
        acc[tm][tn] = __builtin_amdgcn_mfma_f32_16x16x32_bf16(af[tm], bfr[tn], acc[tm][tn], 0, 0, 0);
  }

#pragma unroll
  for (int tm = 0; tm < 2; ++tm) {
    int r0 = rowBase + wm + tm * 16 + kg * 4;
#pragma unroll
    for (int tn = 0; tn < NT; ++tn) {
      int c0 = wn + tn * 16 + lm;
#pragma unroll
      for (int r = 0; r < 4; ++r) {
        int gr = r0 + r;
        if (full || gr < NN) {
          float val = acc[tm][tn][r] * dis[gr];
          if constexpr (OUT8) {
            unsigned char* o8 = (unsigned char*)outv;
            unsigned pk = __builtin_amdgcn_cvt_pk_fp8_f32(val, val, 0, 0);
            o8[(size_t)gr * BN + c0] = (unsigned char)(pk & 0xffu);
          } else {
            __bf16* ob = (__bf16*)outv;
            ob[(size_t)gr * BN + c0] = (__bf16)val;
          }
        }
      }
    }
  }
}

// ---------------- FUSED agg(fp8 gather) + GEMM: tile's aggregation fills LDS A, then MFMA ----------------
// agg output for node n IS GEMM row n (node-local dependency) -> fuse per 128-node
// tile. Kills the 25.6MB d_out roundtrip AND the GEMM's latency-bound global A-path
// (gather IS the A-fetch; GEMM reads LDS). Gather phase = R8's node-quad structure
// (4 nodes/wave x 16-lane groups), 4 iterations covering the tile's 128 nodes.
// Numerics identical: same bf16 intermediate, same relu((f32)a + bias) chain.

template <int BN, bool OUT8>
__global__ __launch_bounds__(512) void k_agg_gemm(const unsigned char* __restrict__ in8,
                                                  const int* __restrict__ row_ptr, const int* __restrict__ csr_src,
                                                  const float* __restrict__ dis, const __bf16* __restrict__ Wt,
                                                  const float* __restrict__ bias, void* __restrict__ outv) {
  constexpr int LDK = 136;
  constexpr int NT = BN / 32;
  constexpr int ROWB = BN * (OUT8 ? 1 : 2);
  __shared__ __bf16 lA[128 * LDK];  // 34816 B aggregated A-tile
  __shared__ __bf16 lB[BN * LDK];   // W tile

  const int tid = threadIdx.x;
  const int tileBase = blockIdx.x * 128;
  const int lane = tid & 63;
  const int wv = tid >> 6;   // 0..7
  const int g = lane >> 4;   // node slot in wave
  const int fl = lane & 15;  // bytes [fl*8, fl*8+8)

  if (blockIdx.x == 0 && tid < ROWB / 16) {  // zero pad row NN of OUR output
    ((uint4*)((char*)outv + (size_t)NN * ROWB))[tid] = make_uint4(0, 0, 0, 0);
  }

  // stage W (global loads overlap the gather phase below)
  for (int c = tid; c < 16 * BN; c += 512) {
    int n = c >> 4;
    int koff = (c & 15) * 8;
    *(bf16x8*)&lB[n * LDK + koff] = *(const bf16x8*)(Wt + n * 128 + koff);
  }

  // ---- gather phase: 4 iterations x 8 waves x 4 nodes = 128 nodes ----
  for (int it = 0; it < 4; ++it) {
    int lrow = it * 32 + wv * 4 + g;  // 0..127
    int node = tileBase + lrow;
    int beg = 0, end = 0;
    if (node < NN) { beg = row_ptr[node]; end = row_ptr[node + 1]; }
    int nd = (node < NN) ? node : NN;  // pad row for OOB

    int mx = end - beg;  // wave-uniform max over the 4 groups
    mx = max(mx, __shfl_xor(mx, 16));
    mx = max(mx, __shfl_xor(mx, 32));

    float acc[8] = {};
    {
      uint2 sv = *(const uint2*)(in8 + (size_t)nd * 128 + fl * 8);
      ACC8_FP8(sv);
    }
    for (int done = 0; done < mx; done += 16) {
      int ep = beg + done + fl;
      int sidx = (ep < end) ? csr_src[ep] : NN;  // NN = zero row
      int rem = mx - done;
      {
        uint2 v[8];
#pragma unroll
        for (int u = 0; u < 8; ++u) {
          int s = __shfl(sidx, g * 16 + u);
          v[u] = *(const uint2*)(in8 + (size_t)s * 128 + fl * 8);
        }
#pragma unroll
        for (int u = 0; u < 8; ++u) ACC8_FP8(v[u]);
      }
      if (rem > 8) {
        uint2 v[8];
#pragma unroll
        for (int u = 0; u < 8; ++u) {
          int s = __shfl(sidx, g * 16 + 8 + u);
          v[u] = *(const uint2*)(in8 + (size_t)s * 128 + fl * 8);
        }
#pragma unroll
        for (int u = 0; u < 8; ++u) ACC8_FP8(v[u]);
      }
    }
    float d = (node < NN) ? dis[node] : 0.f;
    bf16x8 o;
#pragma unroll
    for (int t = 0; t < 8; ++t) o[t] = (__bf16)(acc[t] * d);
    *(bf16x8*)&lA[lrow * LDK + fl * 8] = o;
  }
  __syncthreads();  // lA + lB complete

  // ---- GEMM phase: A from LDS, relu(a+bias) prep, MFMA ----
  const int wm = (wv & 3) * 32;
  const int wn = (wv >> 2) * (BN / 2);
  const int lm = lane & 15;
  const int kg = lane >> 4;
  const bool full = (tileBase + 128 <= NN);

  f32x4 acc2[2][NT] = {};
#pragma unroll 2
  for (int ks = 0; ks < 128; ks += 32) {
    int k0 = ks + kg * 8;
    f32x4 b0 = *(const f32x4*)(bias + k0);
    f32x4 b1 = *(const f32x4*)(bias + k0 + 4);
    bf16x8 af[2];
#pragma unroll
    for (int tm = 0; tm < 2; ++tm) {
      int lr = wm + tm * 16 + lm;
      bf16x8 v = *(const bf16x8*)&lA[lr * LDK + k0];
      af[tm] = bf16x8{(__bf16)fmaxf((float)v[0] + b0[0], 0.f), (__bf16)fmaxf((float)v[1] + b0[1], 0.f),
                      (__bf16)fmaxf((float)v[2] + b0[2], 0.f), (__bf16)fmaxf((float)v[3] + b0[3], 0.f),
                      (__bf16)fmaxf((float)v[4] + b1[0], 0.f), (__bf16)fmaxf((float)v[5] + b1[1], 0.f),
                      (__bf16)fmaxf((float)v[6] + b1[2], 0.f), (__bf16)fmaxf((float)v[7] + b1[3], 0.f)};
    }
    bf16x8 bfr[NT];
#pragma unroll
    for (int tn = 0; tn < NT; ++tn)
      bfr[tn] = *(const bf16x8*)&lB[(wn + tn * 16 + lm) * LDK + k0];
#pragma unroll
    for (int tm = 0; tm < 2; ++tm)
#pragma unroll
      for (int tn = 0; tn < NT; ++tn)
        acc2[tm][tn] = __builtin_amdgcn_mfma_f32_16x16x32_bf16(af[tm], bfr[tn], acc2[tm][tn], 0, 0, 0);
  }

  // epilogue: C/D layout col=lane&15, row=(lane>>4)*4+reg; scale by dis[row]
#pragma unroll
  for (int tm = 0; tm < 2; ++tm) {
    int r0 = tileBase + wm + tm * 16 + kg * 4;
#pragma unroll
    for (int tn = 0; tn < NT; ++tn) {
      int c0 = wn + tn * 16 + lm;
#pragma unroll
      for (int r = 0; r < 4; ++r) {
        int gr = r0 + r;
        if (full || gr < NN) {
          float val = acc2[tm][tn][r] * dis[gr];
          if constexpr (OUT8) {
            unsigned char* o8 = (unsigned char*)outv;
            unsigned pk = __builtin_amdgcn_cvt_pk_fp8_f32(val, val, 0, 0);
            o8[(size_t)gr * BN + c0] = (unsigned char)(pk & 0xffu);
          } else {
            __bf16* ob = (__bf16*)outv;
            ob[(size_t)gr * BN + c0] = (__bf16)val;
          }
        }
      }
    }
  }
}

// ---------------- node-quad F=64 aggregation + bias+relu+log_softmax (final layer) ----------------

__global__ __launch_bounds__(256) void k_agg64_final(const __bf16* __restrict__ tmp, const int* __restrict__ row_ptr,
                                                     const int* __restrict__ csr_src, const float* __restrict__ dis,
                                                     const float* __restrict__ b2, float* __restrict__ out) {
  int qw = (blockIdx.x * 256 + threadIdx.x) >> 6;
  int lane = threadIdx.x & 63;
  int g = lane >> 4;        // group 0..3 -> node slot
  int fl = lane & 15;       // features [fl*4, fl*4+4)
  int node = qw * 4 + g;

  int beg = row_ptr[node];
  int end = row_ptr[node + 1];

  int mx = end - beg;
  mx = max(mx, __shfl_xor(mx, 16));
  mx = max(mx, __shfl_xor(mx, 32));

  float acc[4] = {};
  {
    bf16x4 sv = *(const bf16x4*)&tmp[(size_t)node * 64 + fl * 4];
#pragma unroll
    for (int t = 0; t < 4; ++t) acc[t] = (float)sv[t];
  }

  for (int done = 0; done < mx; done += 16) {
    int ep = beg + done + fl;
    int sidx = (ep < end) ? csr_src[ep] : NN;  // NN = zero row
    int rem = mx - done;
    {
      bf16x4 v[8];
#pragma unroll
      for (int u = 0; u < 8; ++u) {
        int s = __shfl(sidx, g * 16 + u);
        v[u] = *(const bf16x4*)&tmp[(size_t)s * 64 + fl * 4];
      }
#pragma unroll
      for (int u = 0; u < 8; ++u)
#pragma unroll
        for (int t = 0; t < 4; ++t) acc[t] += (float)v[u][t];
    }
    if (rem > 8) {
      bf16x4 v[8];
#pragma unroll
      for (int u = 0; u < 8; ++u) {
        int s = __shfl(sidx, g * 16 + 8 + u);
        v[u] = *(const bf16x4*)&tmp[(size_t)s * 64 + fl * 4];
      }
#pragma unroll
      for (int u = 0; u < 8; ++u)
#pragma unroll
        for (int t = 0; t < 4; ++t) acc[t] += (float)v[u][t];
    }
  }

  float d = dis[node];
  float v4[4], lm = -1e30f;
#pragma unroll
  for (int t = 0; t < 4; ++t) {
    v4[t] = fmaxf(acc[t] * d + b2[fl * 4 + t], 0.f);
    lm = fmaxf(lm, v4[t]);
  }
#pragma unroll
  for (int off = 8; off > 0; off >>= 1) lm = fmaxf(lm, __shfl_xor(lm, off));
  float le = 0.f;
#pragma unroll
  for (int t = 0; t < 4; ++t) le += __expf(v4[t] - lm);
#pragma unroll
  for (int off = 8; off > 0; off >>= 1) le += __shfl_xor(le, off);
  float ls = lm + __logf(le);
  f32x4 o = {v4[0] - ls, v4[1] - ls, v4[2] - ls, v4[3] - ls};
  *(f32x4*)&out[(size_t)node * 64 + fl * 4] = o;
}

// ---------------- launch ----------------

extern "C" void kernel_launch(void* const* d_in, const int* in_sizes, int n_in,
                              void* d_out, int out_size, void* d_ws, size_t ws_size,
                              hipStream_t stream) {
  const float* x  = (const float*)d_in[0];
  const int*   ei = (const int*)d_in[1];
  const float* W0 = (const float*)d_in[2];
  const float* b0 = (const float*)d_in[3];
  const float* W1 = (const float*)d_in[4];
  const float* b1 = (const float*)d_in[5];
  const float* W2 = (const float*)d_in[6];
  const float* b2 = (const float*)d_in[7];
  const int* esrc = ei;
  const int* edst = ei + NE;

  char* p = (char*)d_ws;
  auto alloc = [&](size_t bytes) {
    char* q = p;
    p += (bytes + 255) & ~(size_t)255;
    return q;
  };
  float*  dis     = (float*)alloc((size_t)NN * 4);
  int*    row_ptr = (int*)alloc((size_t)(NN + 1) * 4);
  int*    btot    = (int*)alloc(NBK * 4);
  int*    bptr    = (int*)alloc((NBK + 1) * 4);
  __bf16* Wt      = (__bf16*)alloc(40960 * 2);                 // 80 KB: Wt0|Wt1|Wt2
  int*    csr_src = (int*)alloc((size_t)NE * 4);               // 6.4 MB
  char*   tmp     = (char*)alloc((size_t)(NN + 1) * 128);      // 12.8 MB fp8 L0 out
  char*   tmp_b   = (char*)alloc((size_t)(NN + 1) * 128);      // 12.8 MB fp8 L1 out (separate: WAR)
  char*   tmp_c   = (char*)alloc((size_t)(NN + 1) * 128);      // 12.8 MB bf16 F=64 L2 out
  unsigned char* tmp8   = (unsigned char*)tmp;
  unsigned char* tmp8_b = (unsigned char*)tmp_b;
  __bf16* tmp16_c = (__bf16*)tmp_c;
  int*    bucketed  = (int*)tmp;                               // 6.4 MB alias (consumed pre-GEMM0)
  int*    bhist     = csr_src;                                 // 1.6 MB alias [bin][block]
  int*    blockbase = csr_src + NBK * NBLK;                    // 1.6 MB alias

  k1_hist<<<NBLK + 160, 256, 0, stream>>>(edst, bhist, W0, W1, W2, Wt);  // + fused W-prep
  kA2<<<(NBK + 3) / 4, 256, 0, stream>>>(bhist, btot);
  kB_bscan<<<1, 1024, 0, stream>>>(btot, bptr);
  kC2<<<(NBK + 3) / 4, 256, 0, stream>>>(bhist, bptr, blockbase);
  k3_scatter<<<NBLK, 256, 0, stream>>>(esrc, edst, blockbase, bucketed);
  k_degfill<<<NBK, 256, 0, stream>>>(bucketed, bptr, row_ptr, dis, csr_src);

  int gblocks = (NN + 127) / 128;  // 782
  int ablocks = NN / 16;           // 6250: 4 waves/block x 4 nodes/wave

  k_gemm<128, 0, true><<<gblocks, 512, 0, stream>>>(x, Wt, nullptr, dis, tmp8);
  k_agg_gemm<128, true><<<gblocks, 512, 0, stream>>>(tmp8, row_ptr, csr_src, dis, Wt + 16384, b0, tmp8_b);
  k_agg_gemm<64, false><<<gblocks, 512, 0, stream>>>(tmp8_b, row_ptr, csr_src, dis, Wt + 32768, b1, tmp16_c);
  k_agg64_final<<<ablocks, 256, 0, stream>>>(tmp16_c, row_ptr, csr_src, dis, b2, (float*)d_out);
}